// Round 1
// baseline (499.711 us; speedup 1.0000x reference)
//
#include <hip/hip_runtime.h>
#include <hip/hip_fp16.h>

// GNN: 3x GCNConv (25->64->64->32) + global mean pool (256 graphs) + MLP head.
// Round 7: fp16 gather payload. The three CSR gathers dominate traffic
// (E*(32+64+32)*4 = 1.64 GB random row reads per launch). Storing the
// gather operands (pre-scaled xp and the (h@W)*dinv GEMM outputs) as
// __half with fp32 accumulation halves random-read bytes and halves
// cache-line transactions per edge. CSR build, GEMM math, pool and head
// remain fp32. Assumes N < 2^17 (N=100000) for the 17-bit src packing.

#define IN_DIM 25
#define HID 64
#define OUT3 32
#define BK_LOG 7
#define BK_NODES 128
#define MAXB 1024
#define EPB1 16384
#define BCAP 8192

__device__ inline int ld_nt_i32(const int* p) {
    return __builtin_nontemporal_load(p);
}

// ---------------- stage 1: bucket histogram (LDS-privatized) ----------------
__global__ __launch_bounds__(256) void bucket_hist(const int* __restrict__ dst,
                                                   int* __restrict__ bhist, int nE) {
    __shared__ int h[MAXB];
    for (int i = threadIdx.x; i < MAXB; i += 256) h[i] = 0;
    __syncthreads();
    int e0 = blockIdx.x * 8192;
    int cnt = min(8192, nE - e0);
    for (int i = threadIdx.x; i < cnt; i += 256)
        atomicAdd(&h[(unsigned)dst[e0 + i] >> BK_LOG], 1);
    __syncthreads();
    for (int i = threadIdx.x; i < MAXB; i += 256)
        if (h[i]) atomicAdd(&bhist[i], h[i]);
}

// ---------------- stage 2: scan bucket counts (1 block) ----------------
__global__ __launch_bounds__(256) void bucket_scan(const int* __restrict__ bhist,
                                                   int* __restrict__ bbase,
                                                   int* __restrict__ cursor,
                                                   int* __restrict__ row_ptr,
                                                   int nb, int nE, int nN) {
    __shared__ int s4[256];
    int t = threadIdx.x;
    int v[4]; int sum = 0;
#pragma unroll
    for (int j = 0; j < 4; ++j) {
        int b = 4 * t + j;
        v[j] = (b < nb) ? bhist[b] : 0;
        sum += v[j];
    }
    s4[t] = sum;
    __syncthreads();
    for (int off = 1; off < 256; off <<= 1) {
        int mine = s4[t];
        int add = (t >= off) ? s4[t - off] : 0;
        __syncthreads();
        s4[t] = mine + add;
        __syncthreads();
    }
    int run = s4[t] - sum;
#pragma unroll
    for (int j = 0; j < 4; ++j) {
        int b = 4 * t + j;
        if (b < nb) { bbase[b] = run; cursor[b] = run; }
        run += v[j];
    }
    if (t == 0) { bbase[nb] = nE; row_ptr[nN] = nE; }
}

// ---------------- stage 3: partition edges into buckets (coalesced) --------
__global__ __launch_bounds__(256) void partition_kernel(
        const int* __restrict__ src, const int* __restrict__ dst,
        int* __restrict__ cursor, unsigned int* __restrict__ ebuf, int nE) {
    __shared__ int lh[MAXB];
    __shared__ int lrun[MAXB];
    __shared__ int lcur[MAXB];
    __shared__ int swp[256];
    __shared__ unsigned int stg[EPB1];
    __shared__ unsigned short sbk[EPB1];
    int t = threadIdx.x;
    int e0 = blockIdx.x * EPB1;
    int cnt = min(EPB1, nE - e0);
    for (int i = t; i < MAXB; i += 256) lh[i] = 0;
    __syncthreads();
    for (int i = t; i < cnt; i += 256)
        atomicAdd(&lh[(unsigned)dst[e0 + i] >> BK_LOG], 1);
    __syncthreads();
    int v[4]; int sum = 0;
#pragma unroll
    for (int j = 0; j < 4; ++j) { v[j] = lh[4 * t + j]; sum += v[j]; }
    swp[t] = sum;
    __syncthreads();
    for (int off = 1; off < 256; off <<= 1) {
        int mine = swp[t];
        int add = (t >= off) ? swp[t - off] : 0;
        __syncthreads();
        swp[t] = mine + add;
        __syncthreads();
    }
    int run = swp[t] - sum;
#pragma unroll
    for (int j = 0; j < 4; ++j) {
        int b = 4 * t + j;
        lh[b] = run;
        lcur[b] = 0;
        if (v[j] > 0) lrun[b] = atomicAdd(&cursor[b], v[j]);
        run += v[j];
    }
    __syncthreads();
    for (int i = t; i < cnt; i += 256) {
        int d = dst[e0 + i];
        int s = src[e0 + i];
        int b = (unsigned)d >> BK_LOG;
        int lp = atomicAdd(&lcur[b], 1);
        int slot = lh[b] + lp;
        stg[slot] = ((unsigned)(d & (BK_NODES - 1)) << 17) | (unsigned)s;
        sbk[slot] = (unsigned short)b;
    }
    __syncthreads();
    for (int i = t; i < cnt; i += 256) {
        int b = sbk[i];
        int g = lrun[b] + (i - lh[b]);
        ebuf[g] = stg[i];
    }
}

// ---------------- stage 4: per-bucket CSR sort + row_ptr + dinv ------------
__global__ __launch_bounds__(256) void bucket_csr_kernel(
        unsigned int* __restrict__ ebuf, const int* __restrict__ bbase,
        float* __restrict__ dinv, int* __restrict__ row_ptr, int nN) {
    int b = blockIdx.x;
    int node_lo = b << BK_LOG;
    int nn = min(BK_NODES, nN - node_lo);
    int base = bbase[b];
    int cnt = bbase[b + 1] - base;
    if (cnt > BCAP) cnt = BCAP;
    __shared__ unsigned int in[BCAP];
    __shared__ unsigned int outb[BCAP];
    __shared__ int h[BK_NODES], sc[BK_NODES], lc[BK_NODES];
    int t = threadIdx.x;
    for (int i = t; i < cnt; i += 256) in[i] = ebuf[base + i];
    if (t < BK_NODES) { h[t] = 0; lc[t] = 0; }
    __syncthreads();
    for (int i = t; i < cnt; i += 256) atomicAdd(&h[in[i] >> 17], 1);
    __syncthreads();
    if (t < BK_NODES) sc[t] = h[t];
    __syncthreads();
    for (int off = 1; off < BK_NODES; off <<= 1) {
        int val = 0;
        if (t < BK_NODES) { val = sc[t]; if (t >= off) val += sc[t - off]; }
        __syncthreads();
        if (t < BK_NODES) sc[t] = val;
        __syncthreads();
    }
    if (t < BK_NODES && t < nn) {
        dinv[node_lo + t] = rsqrtf((float)h[t] + 1.0f);
        row_ptr[node_lo + t] = base + (sc[t] - h[t]);
    }
    __syncthreads();
    for (int i = t; i < cnt; i += 256) {
        unsigned int w = in[i];
        int dl = w >> 17;
        int lp = atomicAdd(&lc[dl], 1);
        outb[(sc[dl] - h[dl]) + lp] = w & 0x1FFFFu;
    }
    __syncthreads();
    for (int i = t; i < cnt; i += 256) ebuf[base + i] = outb[i];
}

// ---------------- pad + pre-scale helpers ----------------
// xp[node][c] = half( x[node][c] * dinv[node] )  (pre-scaled gather operand)
__global__ void padx_kernel(const float* __restrict__ x, const float* __restrict__ dinv,
                            __half* __restrict__ xp, int n) {
    int i = blockIdx.x * 256 + threadIdx.x;   // one thread per 2 cols
    if (i < n * 16) {
        int node = i >> 4, c2 = (i & 15) * 2;
        float s = dinv[node];
        float v0 = (c2     < IN_DIM) ? x[(size_t)node * IN_DIM + c2    ] * s : 0.f;
        float v1 = (c2 + 1 < IN_DIM) ? x[(size_t)node * IN_DIM + c2 + 1] * s : 0.f;
        *(__half2*)&xp[(size_t)node * 32 + c2] = __floats2half2_rn(v0, v1);
    }
}

__global__ void padw_kernel(const float* __restrict__ W1, float* __restrict__ W1p) {
    int i = blockIdx.x * 256 + threadIdx.x;
    if (i < 32 * HID) {
        int r = i >> 6, c = i & 63;
        W1p[i] = (r < IN_DIM) ? W1[r * HID + c] : 0.f;
    }
}

// ---------------- dense layer: out = in @ W [*dinv->half] [+bias,relu] -----
// SCALE=true writes __half (gather operand); SCALE=false writes float.
template<int INF, int OUTF, bool ACT, bool SCALE>
__global__ __launch_bounds__(256) void gemm_kernel(
        const float* __restrict__ in, const float* __restrict__ W,
        const float* __restrict__ bias, const float* __restrict__ dinv,
        void* __restrict__ out, int n) {
    constexpr int TPN = OUTF / 4;
    constexpr int NPB = 256 / TPN;
    constexpr int LDK = INF + 4;
    __shared__ float sW[INF * OUTF];
    __shared__ float sIn[NPB][LDK];
    for (int i = threadIdx.x; i < INF * OUTF; i += 256) sW[i] = W[i];
    int node0 = blockIdx.x * NPB;
    for (int i = threadIdx.x; i < NPB * INF; i += 256) {
        int ln = i / INF, k = i % INF;
        int node = node0 + ln;
        sIn[ln][k] = (node < n) ? in[(size_t)node * INF + k] : 0.f;
    }
    __syncthreads();
    int g   = threadIdx.x / TPN;
    int of0 = (threadIdx.x % TPN) * 4;
    int node = node0 + g;
    float4 acc = make_float4(0.f, 0.f, 0.f, 0.f);
#pragma unroll
    for (int k = 0; k < INF; ++k) {
        float aj = sIn[g][k];
        const float4 wv = *(const float4*)&sW[k * OUTF + of0];
        acc.x += aj * wv.x; acc.y += aj * wv.y;
        acc.z += aj * wv.z; acc.w += aj * wv.w;
    }
    if (ACT) {
        const float4 bv = *(const float4*)&bias[of0];
        acc.x = fmaxf(acc.x + bv.x, 0.f);
        acc.y = fmaxf(acc.y + bv.y, 0.f);
        acc.z = fmaxf(acc.z + bv.z, 0.f);
        acc.w = fmaxf(acc.w + bv.w, 0.f);
    }
    if (node < n) {
        if (SCALE) {
            float s = dinv[node];
            union { __half2 h[2]; uint2 u; } pk;
            pk.h[0] = __floats2half2_rn(acc.x * s, acc.y * s);
            pk.h[1] = __floats2half2_rn(acc.z * s, acc.w * s);
            *(uint2*)((__half*)out + (size_t)node * OUTF + of0) = pk.u;
        } else {
            *(float4*)((float*)out + (size_t)node * OUTF + of0) = acc;
        }
    }
}

// ---------------- CSR gather on PRE-SCALED fp16 rows ----------------
// out[d] = act( dinv[d] * (hp[d] + sum_cols hp[c]) + bias )
// inner loop: col load -> hp half load -> fp32 add. 16-deep, 4 accumulators.
template<int F, bool ACT>
__global__ __launch_bounds__(256) void gather_kernel(
        const __half* __restrict__ hp, const float* __restrict__ dinv,
        const int* __restrict__ row_ptr, const int* __restrict__ col,
        const float* __restrict__ bias, float* __restrict__ agg, int n) {
    constexpr int NPW = 64 / F;
    int wid  = (blockIdx.x * 256 + threadIdx.x) >> 6;
    int lane = threadIdx.x & 63;
    int sub  = lane / F;
    int f    = lane % F;
    int node = wid * NPW + sub;
    if (node >= n) return;
    float a0 = __half2float(hp[(size_t)node * F + f]);   // self loop (pre-scaled)
    float a1 = 0.f, a2 = 0.f, a3 = 0.f;
    int e = row_ptr[node], end = row_ptr[node + 1];
    for (; e + 16 <= end; e += 16) {
        int c[16];
#pragma unroll
        for (int j = 0; j < 16; ++j) c[j] = ld_nt_i32(&col[e + j]);
        float v[16];
#pragma unroll
        for (int j = 0; j < 16; ++j) v[j] = __half2float(hp[(size_t)c[j] * F + f]);
#pragma unroll
        for (int j = 0; j < 4; ++j) {
            a0 += v[4 * j];     a1 += v[4 * j + 1];
            a2 += v[4 * j + 2]; a3 += v[4 * j + 3];
        }
    }
    for (; e + 4 <= end; e += 4) {
        int c0 = ld_nt_i32(&col[e]),     c1 = ld_nt_i32(&col[e + 1]);
        int c2 = ld_nt_i32(&col[e + 2]), c3 = ld_nt_i32(&col[e + 3]);
        a0 += __half2float(hp[(size_t)c0 * F + f]);
        a1 += __half2float(hp[(size_t)c1 * F + f]);
        a2 += __half2float(hp[(size_t)c2 * F + f]);
        a3 += __half2float(hp[(size_t)c3 * F + f]);
    }
    for (; e < end; ++e) a0 += __half2float(hp[(size_t)ld_nt_i32(&col[e]) * F + f]);
    float acc = ((a0 + a1) + (a2 + a3)) * dinv[node];
    float r = ACT ? fmaxf(acc + bias[f], 0.f) : acc;
    agg[(size_t)node * F + f] = r;
}

// ---------------- mean pool ----------------
__global__ __launch_bounds__(256) void pool_kernel(
        const float* __restrict__ h3, const int* __restrict__ batch,
        int n, float* __restrict__ pool) {
    int g = blockIdx.x;
    int lo = 0, hi = n;
    while (lo < hi) { int m = (lo + hi) >> 1; if (batch[m] < g) lo = m + 1; else hi = m; }
    int s = lo;
    hi = n;
    while (lo < hi) { int m = (lo + hi) >> 1; if (batch[m] < g + 1) lo = m + 1; else hi = m; }
    int e = lo;
    constexpr int F = OUT3;
    int ln = threadIdx.x / F;
    int f  = threadIdx.x % F;
    float acc = 0.f;
    for (int i = s + ln; i < e; i += 8)
        acc += h3[(size_t)i * F + f];
    __shared__ float red[8][F];
    red[ln][f] = acc;
    __syncthreads();
    if (ln == 0) {
        float t = 0.f;
#pragma unroll
        for (int j = 0; j < 8; ++j) t += red[j][f];
        float cnt = (float)((e - s) > 0 ? (e - s) : 1);
        pool[g * F + f] = t / cnt;
    }
}

// ---------------- head ----------------
__global__ __launch_bounds__(256) void head_kernel(
        const float* __restrict__ pool, const float* __restrict__ Wh1,
        const float* __restrict__ bh1, const float* __restrict__ Wh2,
        const float* __restrict__ bh2, float* __restrict__ out) {
    __shared__ float sW1[32 * 32];
    __shared__ float sb1[32];
    __shared__ float sW2[32];
    int t = threadIdx.x;
    for (int i = t; i < 1024; i += 256) sW1[i] = Wh1[i];
    if (t < 32) { sb1[t] = bh1[t]; sW2[t] = Wh2[t]; }
    __syncthreads();
    int g = t;
    float y = bh2[0];
    const float* p = &pool[g * 32];
#pragma unroll 4
    for (int j = 0; j < 32; ++j) {
        float a = sb1[j];
#pragma unroll
        for (int k = 0; k < 32; ++k) a += p[k] * sW1[k * 32 + j];
        y += fmaxf(a, 0.f) * sW2[j];
    }
    out[g] = y;
}

extern "C" void kernel_launch(void* const* d_in, const int* in_sizes, int n_in,
                              void* d_out, int out_size, void* d_ws, size_t ws_size,
                              hipStream_t stream) {
    const float* x    = (const float*)d_in[0];
    const int*   ei   = (const int*)  d_in[1];
    const int*   batch= (const int*)  d_in[2];
    const float* W1   = (const float*)d_in[3];
    const float* b1   = (const float*)d_in[4];
    const float* W2   = (const float*)d_in[5];
    const float* b2   = (const float*)d_in[6];
    const float* W3   = (const float*)d_in[7];
    const float* b3   = (const float*)d_in[8];
    const float* Wh1  = (const float*)d_in[9];
    const float* bh1  = (const float*)d_in[10];
    const float* Wh2  = (const float*)d_in[11];
    const float* bh2  = (const float*)d_in[12];
    float* out = (float*)d_out;

    const int N = in_sizes[0] / IN_DIM;
    const int E = in_sizes[1] / 2;
    const int* src = ei;
    const int* dst = ei + E;
    const int NB = (N + BK_NODES - 1) >> BK_LOG;

    // workspace layout (all 4B elements; half buffers alias the fp32 ones)
    char* base = (char*)d_ws;
    unsigned int* ebuf = (unsigned int*)base;       base += (size_t)E * 4;
    int*   bhist   = (int*)base;                    base += (size_t)MAXB * 4;
    int*   bbase   = (int*)base;                    base += (size_t)(MAXB + 1) * 4;
    int*   cursor  = (int*)base;                    base += (size_t)MAXB * 4;
    int*   row_ptr = (int*)base;                    base += (size_t)(N + 1) * 4;
    float* dinv    = (float*)base;                  base += (size_t)N * 4;
    float* W1p     = (float*)base;                  base += (size_t)32 * HID * 4;
    float* bufA    = (float*)base;                  base += (size_t)N * HID * 4;
    float* bufB    = (float*)base;                  base += (size_t)N * HID * 4;
    float* pool    = (float*)base;

    // ---- CSR build (coalesced counting sort) ----
    hipMemsetAsync(bhist, 0, (size_t)MAXB * sizeof(int), stream);
    bucket_hist<<<(E + 8191) / 8192, 256, 0, stream>>>(dst, bhist, E);
    bucket_scan<<<1, 256, 0, stream>>>(bhist, bbase, cursor, row_ptr, NB, E, N);
    partition_kernel<<<(E + EPB1 - 1) / EPB1, 256, 0, stream>>>(src, dst, cursor, ebuf, E);
    bucket_csr_kernel<<<NB, 256, 0, stream>>>(ebuf, bbase, dinv, row_ptr, N);
    const int* col = (const int*)ebuf;

    // ---- layer 1 (reordered): aggX = A_hat Xp' ; h1 = relu(aggX @ W1p + b1)
    // xp (half) in bufB; aggX (fp32) in bufA; h1 (fp32) back in bufB.
    padx_kernel<<<((size_t)N * 16 + 255) / 256, 256, 0, stream>>>(x, dinv, (__half*)bufB, N);
    padw_kernel<<<(32 * HID + 255) / 256, 256, 0, stream>>>(W1, W1p);
    gather_kernel<32, false><<<(N + 7) / 8, 256, 0, stream>>>((const __half*)bufB, dinv, row_ptr, col, nullptr, bufA, N);
    gemm_kernel<32, HID, true, false><<<(N + 15) / 16, 256, 0, stream>>>(bufA, W1p, b1, nullptr, bufB, N);

    // ---- layer 2: t2' = half((h1 @ W2)*dinv) ; h2 = relu(dinv*(sum t2') + b2)
    gemm_kernel<HID, HID, false, true><<<(N + 15) / 16, 256, 0, stream>>>(bufB, W2, nullptr, dinv, bufA, N);
    gather_kernel<HID, true><<<(N + 3) / 4, 256, 0, stream>>>((const __half*)bufA, dinv, row_ptr, col, b2, bufB, N);

    // ---- layer 3: t3' = half((h2 @ W3)*dinv) ; h3 = relu(dinv*(sum t3') + b3)
    gemm_kernel<HID, OUT3, false, true><<<(N + 31) / 32, 256, 0, stream>>>(bufB, W3, nullptr, dinv, bufA, N);
    gather_kernel<OUT3, true><<<(N + 7) / 8, 256, 0, stream>>>((const __half*)bufA, dinv, row_ptr, col, b3, bufB, N);

    // ---- pool + head ----
    pool_kernel<<<256, 256, 0, stream>>>(bufB, batch, N, pool);
    head_kernel<<<1, 256, 0, stream>>>(pool, Wh1, bh1, Wh2, bh2, out);
}